// Round 18
// baseline (640.824 us; speedup 1.0000x reference)
//
#include <hip/hip_runtime.h>
#include <hip/hip_bf16.h>
#include <cfloat>
#include <cmath>

#define SEQ 4096
#define DIM 768
#define NH 12
#define HD 64
#define NEG_MASK (-0x1.FEp+127f)

typedef __attribute__((ext_vector_type(8))) short short8_t;  // 8 bf16
typedef __attribute__((ext_vector_type(4))) float f32x4;     // MFMA C/D

static __device__ __forceinline__ unsigned short f2bf(float f) {
  __hip_bfloat16 h = __float2bfloat16(f);
  unsigned short u;
  __builtin_memcpy(&u, &h, 2);
  return u;
}

static __device__ __forceinline__ f32x4 ld_lds4(const float* p) {
  return *(const f32x4*)p;
}

// ---------------- LayerNorm -> bf16 ----------------
__global__ __launch_bounds__(256) void ln_kernel(const float* __restrict__ x,
    const float* __restrict__ gamma, const float* __restrict__ beta,
    unsigned short* __restrict__ xnb) {
  int row = blockIdx.x;
  const float* xr = x + (size_t)row * DIM;
  int t = threadIdx.x;
  float v0 = xr[t], v1 = xr[t + 256], v2 = xr[t + 512];
  float s = v0 + v1 + v2;
  float s2 = v0 * v0 + v1 * v1 + v2 * v2;
  for (int off = 32; off > 0; off >>= 1) {
    s += __shfl_down(s, off, 64);
    s2 += __shfl_down(s2, off, 64);
  }
  __shared__ float red[2][4];
  int wid = t >> 6;
  if ((t & 63) == 0) { red[0][wid] = s; red[1][wid] = s2; }
  __syncthreads();
  s = red[0][0] + red[0][1] + red[0][2] + red[0][3];
  s2 = red[1][0] + red[1][1] + red[1][2] + red[1][3];
  float mu = s * (1.0f / DIM);
  float var = s2 * (1.0f / DIM) - mu * mu;
  float rstd = rsqrtf(var + 1e-5f);
  unsigned short* xo = xnb + (size_t)row * DIM;
  xo[t]       = f2bf((v0 - mu) * rstd * gamma[t]       + beta[t]);
  xo[t + 256] = f2bf((v1 - mu) * rstd * gamma[t + 256] + beta[t + 256]);
  xo[t + 512] = f2bf((v2 - mu) * rstd * gamma[t + 512] + beta[t + 512]);
}

// ---------------- weight f32 -> bf16 convert (4 matrices) ----------------
__global__ __launch_bounds__(256) void wcvt_kernel(const float* __restrict__ w0,
    const float* __restrict__ w1, const float* __restrict__ w2, const float* __restrict__ w3,
    unsigned short* __restrict__ o0, unsigned short* __restrict__ o1,
    unsigned short* __restrict__ o2, unsigned short* __restrict__ o3) {
  const float* src; unsigned short* dst;
  switch (blockIdx.y) {
    case 0: src = w0; dst = o0; break;
    case 1: src = w1; dst = o1; break;
    case 2: src = w2; dst = o2; break;
    default: src = w3; dst = o3; break;
  }
  size_t base = ((size_t)blockIdx.x * 256 + threadIdx.x) * 8;
  float4 a = *(const float4*)(src + base);
  float4 b = *(const float4*)(src + base + 4);
  ushort4 ua, ub;
  ua.x = f2bf(a.x); ua.y = f2bf(a.y); ua.z = f2bf(a.z); ua.w = f2bf(a.w);
  ub.x = f2bf(b.x); ub.y = f2bf(b.y); ub.z = f2bf(b.z); ub.w = f2bf(b.w);
  *(ushort4*)(dst + base) = ua;
  *(ushort4*)(dst + base + 4) = ub;
}

// ------- QKV MFMA GEMM + fused RoPE -> bf16 q,k and transposed bf16 v -------
__global__ __launch_bounds__(256) void qkv_kernel(const unsigned short* __restrict__ xnb,
    const unsigned short* __restrict__ wqb, const unsigned short* __restrict__ wkb,
    const unsigned short* __restrict__ wvb, const float* __restrict__ ropes,
    unsigned short* __restrict__ qb, unsigned short* __restrict__ kb,
    unsigned short* __restrict__ vbT) {
  int z = blockIdx.z;
  const unsigned short* W = (z == 0) ? wqb : (z == 1) ? wkb : wvb;
  int h = blockIdx.y;
  int n0 = h * 64;
  int tid = threadIdx.x;
  int w = tid >> 6, l = tid & 63;
  int col_l = l & 15, rowg = l >> 4, kgrp = rowg * 8;
  int mbase = blockIdx.x * 64 + w * 16;

  f32x4 acc[4];
  #pragma unroll
  for (int g = 0; g < 4; g++) acc[g] = (f32x4){0.f, 0.f, 0.f, 0.f};

  for (int k0 = 0; k0 < DIM; k0 += 32) {
    short8_t a = *(const short8_t*)(xnb + (size_t)(mbase + col_l) * DIM + k0 + kgrp);
    #pragma unroll
    for (int g = 0; g < 4; g++) {
      short8_t bw = *(const short8_t*)(W + (size_t)(n0 + g * 16 + col_l) * DIM + k0 + kgrp);
      acc[g] = __builtin_amdgcn_mfma_f32_16x16x32_bf16(a, bw, acc[g], 0, 0, 0);
    }
  }

  // RoPE: d = g*16+col_l, partner d^32 -> acc[g^2], same lane
  float res[4][4];
  #pragma unroll
  for (int g = 0; g < 4; g++) {
    int d = g * 16 + col_l;
    #pragma unroll
    for (int r = 0; r < 4; r++) {
      int m = mbase + rowg * 4 + r;
      float f = ropes[(size_t)m * HD + d];
      float val = acc[g][r];
      float oth = acc[g ^ 2][r];
      float rot = (g < 2) ? -oth : oth;
      res[g][r] = val * cosf(f) + rot * sinf(f);
    }
  }

  if (z < 2) {
    unsigned short* dst = (z == 0) ? qb : kb;
    #pragma unroll
    for (int g = 0; g < 4; g++) {
      int d = g * 16 + col_l;
      #pragma unroll
      for (int r = 0; r < 4; r++)
        dst[((size_t)h * SEQ + mbase + rowg * 4 + r) * HD + d] = f2bf(res[g][r]);
    }
  } else {
    #pragma unroll
    for (int g = 0; g < 4; g++) {
      int d = g * 16 + col_l;
      ushort4 u;
      u.x = f2bf(res[g][0]); u.y = f2bf(res[g][1]);
      u.z = f2bf(res[g][2]); u.w = f2bf(res[g][3]);
      *(ushort4*)(vbT + ((size_t)h * HD + d) * SEQ + mbase + rowg * 4) = u;
    }
  }
}

// ------- fused attention: flat grid + XCD-clustered (h, band) mapping -------
// No-max softmax: logits bounded (|s| << 80) so attn = exp(s)/sum(exp(s));
// masked s = NEG_MASK -> exp == 0. All stores normal (cacheable) — A/B vs NT.
__global__ __launch_bounds__(256, 4) void attn_fused(
    const unsigned short* __restrict__ qb, const unsigned short* __restrict__ kb,
    const unsigned short* __restrict__ vbT,
    float* __restrict__ dots, float* __restrict__ attnp, unsigned short* __restrict__ ob) {
  int bid = blockIdx.x;                 // 0..3071
  int g_ = (bid & 7) * 384 + (bid >> 3);
  int h = g_ >> 8;                      // 0..11
  int band = 255 - (g_ & 255);          // compute-heavy bands first within chunk
  int i0 = band * 16;
  int jd = i0 >> 6;                    // diagonal 64-tile index
  int tid = threadIdx.x;
  int w = tid >> 6, l = tid & 63;
  int col_l = l & 15, rg = l >> 4, kgrp = rg * 8;
  int c4 = col_l * 4;

  const unsigned short* qh = qb + (size_t)h * SEQ * HD;
  const unsigned short* kh = kb + (size_t)h * SEQ * HD;
  const unsigned short* vh = vbT + (size_t)h * HD * SEQ;
  size_t obase = (size_t)h * SEQ * SEQ;

  __shared__ float pt[4][16][68];
  __shared__ float stats[4][16];       // per-wave row sums

  const unsigned short* qrow = qh + (size_t)(i0 + col_l) * HD + kgrp;
  short8_t aq0 = *(const short8_t*)(qrow);
  short8_t aq1 = *(const short8_t*)(qrow + 32);

  float lsum[4];
  #pragma unroll
  for (int r = 0; r < 4; r++) lsum[r] = 0.f;

  // ---- pass 1: dots + per-lane plain sums ----
  for (int jt = w; jt <= jd; jt += 4) {
    int j0 = jt * 64;
    f32x4 acc[4];
    #pragma unroll
    for (int b = 0; b < 4; b++) {
      const unsigned short* kr = kh + (size_t)(j0 + b * 16 + col_l) * HD + kgrp;
      short8_t bk0 = *(const short8_t*)(kr);
      short8_t bk1 = *(const short8_t*)(kr + 32);
      f32x4 z = {0.f, 0.f, 0.f, 0.f};
      acc[b] = __builtin_amdgcn_mfma_f32_16x16x32_bf16(aq0, bk0, z, 0, 0, 0);
      acc[b] = __builtin_amdgcn_mfma_f32_16x16x32_bf16(aq1, bk1, acc[b], 0, 0, 0);
    }
    bool diag = (jt == jd);
    #pragma unroll
    for (int b = 0; b < 4; b++) {
      int j = j0 + b * 16 + col_l;
      #pragma unroll
      for (int r = 0; r < 4; r++) {
        float s = acc[b][r] * 0.125f;
        acc[b][r] = (diag && j > i0 + rg * 4 + r) ? NEG_MASK : s;
      }
    }
    #pragma unroll
    for (int r = 0; r < 4; r++) {
      lsum[r] += __expf(acc[0][r]) + __expf(acc[1][r]) +
                 __expf(acc[2][r]) + __expf(acc[3][r]);
    }
    // stage + contiguous f32x4 dots write (normal store)
    #pragma unroll
    for (int b = 0; b < 4; b++)
      #pragma unroll
      for (int r = 0; r < 4; r++)
        pt[w][rg * 4 + r][b * 16 + col_l] = acc[b][r];
    #pragma unroll
    for (int e = 0; e < 4; e++) {
      f32x4 v = ld_lds4(&pt[w][e * 4 + rg][c4]);
      *(f32x4*)(dots + obase + (size_t)(i0 + e * 4 + rg) * SEQ + j0 + c4) = v;
    }
  }

  // ---- reduction: 16-lane sum + 4-wave sum via LDS ----
  #pragma unroll
  for (int r = 0; r < 4; r++) {
    #pragma unroll
    for (int off = 1; off < 16; off <<= 1)
      lsum[r] += __shfl_xor(lsum[r], off, 16);
  }
  if (col_l == 0) {
    #pragma unroll
    for (int r = 0; r < 4; r++)
      stats[w][rg * 4 + r] = lsum[r];
  }
  __syncthreads();
  float rl_[4];
  #pragma unroll
  for (int r = 0; r < 4; r++) {
    int row = rg * 4 + r;
    rl_[r] = 1.0f / (stats[0][row] + stats[1][row] + stats[2][row] + stats[3][row]);
  }

  // ---- pass 2: attn + partial PV ----
  f32x4 o[4];
  #pragma unroll
  for (int dg = 0; dg < 4; dg++) o[dg] = (f32x4){0.f, 0.f, 0.f, 0.f};

  for (int jt = w; jt <= jd; jt += 4) {
    int j0 = jt * 64;
    f32x4 acc[4];
    #pragma unroll
    for (int b = 0; b < 4; b++) {
      const unsigned short* kr = kh + (size_t)(j0 + b * 16 + col_l) * HD + kgrp;
      short8_t bk0 = *(const short8_t*)(kr);
      short8_t bk1 = *(const short8_t*)(kr + 32);
      f32x4 z = {0.f, 0.f, 0.f, 0.f};
      acc[b] = __builtin_amdgcn_mfma_f32_16x16x32_bf16(aq0, bk0, z, 0, 0, 0);
      acc[b] = __builtin_amdgcn_mfma_f32_16x16x32_bf16(aq1, bk1, acc[b], 0, 0, 0);
    }
    bool diag = (jt == jd);
    #pragma unroll
    for (int b = 0; b < 4; b++) {
      int j = j0 + b * 16 + col_l;
      #pragma unroll
      for (int r = 0; r < 4; r++) {
        float s = acc[b][r] * 0.125f;
        s = (diag && j > i0 + rg * 4 + r) ? NEG_MASK : s;
        float p = __expf(s) * rl_[r];
        pt[w][rg * 4 + r][b * 16 + col_l] = p;
      }
    }
    // contiguous f32x4 attn write (normal store)
    #pragma unroll
    for (int e = 0; e < 4; e++) {
      f32x4 v = ld_lds4(&pt[w][e * 4 + rg][c4]);
      *(f32x4*)(attnp + obase + (size_t)(i0 + e * 4 + rg) * SEQ + j0 + c4) = v;
    }
    // wave-local transpose -> PV
    short8_t pa[2];
    #pragma unroll
    for (int ks = 0; ks < 2; ks++) {
      const float* src = &pt[w][col_l][ks * 32 + kgrp];
      f32x4 x0 = ld_lds4(src);
      f32x4 x1 = ld_lds4(src + 4);
      short8_t t;
      t[0] = (short)f2bf(x0.x); t[1] = (short)f2bf(x0.y);
      t[2] = (short)f2bf(x0.z); t[3] = (short)f2bf(x0.w);
      t[4] = (short)f2bf(x1.x); t[5] = (short)f2bf(x1.y);
      t[6] = (short)f2bf(x1.z); t[7] = (short)f2bf(x1.w);
      pa[ks] = t;
    }
    #pragma unroll
    for (int dg = 0; dg < 4; dg++) {
      const unsigned short* vr = vh + (size_t)(dg * 16 + col_l) * SEQ + j0 + kgrp;
      short8_t bv0 = *(const short8_t*)(vr);
      short8_t bv1 = *(const short8_t*)(vr + 32);
      o[dg] = __builtin_amdgcn_mfma_f32_16x16x32_bf16(pa[0], bv0, o[dg], 0, 0, 0);
      o[dg] = __builtin_amdgcn_mfma_f32_16x16x32_bf16(pa[1], bv1, o[dg], 0, 0, 0);
    }
  }

  // ---- masked-region fill: cols >= (jd+1)*64, rows i0..i0+15 (normal stores) ----
  {
    int c0 = (jd + 1) * 64;
    int nf4 = (SEQ - c0) >> 2;
    if (nf4 > 0) {
      f32x4 dm = (f32x4){NEG_MASK, NEG_MASK, NEG_MASK, NEG_MASK};
      f32x4 zz = (f32x4){0.f, 0.f, 0.f, 0.f};
      for (int r16 = 0; r16 < 16; r16++) {
        f32x4* dr = (f32x4*)(dots  + obase + (size_t)(i0 + r16) * SEQ + c0);
        f32x4* ar = (f32x4*)(attnp + obase + (size_t)(i0 + r16) * SEQ + c0);
        for (int c = tid; c < nf4; c += 256) {
          dr[c] = dm;
          ar[c] = zz;
        }
      }
    }
  }

  // ---- cross-wave O reduce -> bf16 ob ----
  __syncthreads();   // all waves done with pt (pass 2)
  #pragma unroll
  for (int dg = 0; dg < 4; dg++)
    #pragma unroll
    for (int r = 0; r < 4; r++)
      pt[w][rg * 4 + r][dg * 16 + col_l] = o[dg][r];
  __syncthreads();
  {
    int idx = tid * 4;                // 0..1020
    int row = idx >> 6, col = idx & 63;
    f32x4 s = ld_lds4(&pt[0][row][col]);
    #pragma unroll
    for (int w2 = 1; w2 < 4; w2++) {
      f32x4 t = ld_lds4(&pt[w2][row][col]);
      s.x += t.x; s.y += t.y; s.z += t.z; s.w += t.w;
    }
    ushort4 u;
    u.x = f2bf(s.x); u.y = f2bf(s.y); u.z = f2bf(s.z); u.w = f2bf(s.w);
    *(ushort4*)(ob + (size_t)(i0 + row) * DIM + h * HD + col) = u;
  }
}

// ---------------- out = o @ Wo^T + bo + residual (MFMA) ----------------
__global__ __launch_bounds__(256) void out_kernel(const unsigned short* __restrict__ ob,
    const unsigned short* __restrict__ wob, const float* __restrict__ bias,
    const float* __restrict__ resid, float* __restrict__ out) {
  int n0 = blockIdx.y * 64;
  int tid = threadIdx.x;
  int w = tid >> 6, l = tid & 63;
  int col_l = l & 15, rowg = l >> 4, kgrp = rowg * 8;
  int mbase = blockIdx.x * 64 + w * 16;

  f32x4 acc[4];
  #pragma unroll
  for (int g = 0; g < 4; g++) acc[g] = (f32x4){0.f, 0.f, 0.f, 0.f};

  for (int k0 = 0; k0 < DIM; k0 += 32) {
    short8_t a = *(const short8_t*)(ob + (size_t)(mbase + col_l) * DIM + k0 + kgrp);
    #pragma unroll
    for (int g = 0; g < 4; g++) {
      short8_t bw = *(const short8_t*)(wob + (size_t)(n0 + g * 16 + col_l) * DIM + k0 + kgrp);
      acc[g] = __builtin_amdgcn_mfma_f32_16x16x32_bf16(a, bw, acc[g], 0, 0, 0);
    }
  }
  #pragma unroll
  for (int g = 0; g < 4; g++) {
    int n = n0 + g * 16 + col_l;
    float bn = bias[n];
    #pragma unroll
    for (int r = 0; r < 4; r++) {
      int m = mbase + rowg * 4 + r;
      out[(size_t)m * DIM + n] = acc[g][r] + bn + resid[(size_t)m * DIM + n];
    }
  }
}

extern "C" void kernel_launch(void* const* d_in, const int* in_sizes, int n_in,
                              void* d_out, int out_size, void* d_ws, size_t ws_size,
                              hipStream_t stream) {
  const float* x     = (const float*)d_in[0];
  const float* Wq    = (const float*)d_in[1];
  const float* Wk    = (const float*)d_in[2];
  const float* Wv    = (const float*)d_in[3];
  const float* Wo    = (const float*)d_in[4];
  const float* bo    = (const float*)d_in[5];
  const float* gamma = (const float*)d_in[6];
  const float* beta  = (const float*)d_in[7];
  const float* rope  = (const float*)d_in[8];

  float* out  = (float*)d_out;                       // [1,4096,768]
  float* attn = out + (size_t)SEQ * DIM;             // [1,12,4096,4096]
  float* dots = attn + (size_t)NH * SEQ * SEQ;       // [1,12,4096,4096]

  char* ws = (char*)d_ws;
  unsigned short* xnb = (unsigned short*)(ws);                    // 6291456 B
  unsigned short* qb  = (unsigned short*)(ws + 6291456);          // 6291456
  unsigned short* kb  = (unsigned short*)(ws + 12582912);         // 6291456
  unsigned short* vbT = (unsigned short*)(ws + 18874368);         // 6291456
  unsigned short* ob  = (unsigned short*)(ws + 25165824);         // 6291456
  unsigned short* wqb = (unsigned short*)(ws + 31457280);         // 1179648
  unsigned short* wkb = (unsigned short*)(ws + 32636928);         // 1179648
  unsigned short* wvb = (unsigned short*)(ws + 33816576);         // 1179648
  unsigned short* wob = (unsigned short*)(ws + 34996224);         // 1179648

  ln_kernel<<<SEQ, 256, 0, stream>>>(x, gamma, beta, xnb);
  wcvt_kernel<<<dim3(288, 4), 256, 0, stream>>>(Wq, Wk, Wv, Wo, wqb, wkb, wvb, wob);
  qkv_kernel<<<dim3(SEQ / 64, NH, 3), 256, 0, stream>>>(xnb, wqb, wkb, wvb, rope, qb, kb, vbT);
  attn_fused<<<3072, 256, 0, stream>>>(qb, kb, vbT, dots, attn, ob);
  out_kernel<<<dim3(SEQ / 64, DIM / 64), 256, 0, stream>>>(ob, wob, bo, x, out);
}

// Round 19
// 560.184 us; speedup vs baseline: 1.1440x; 1.1440x over previous
//
#include <hip/hip_runtime.h>
#include <hip/hip_bf16.h>
#include <cfloat>
#include <cmath>

#define SEQ 4096
#define DIM 768
#define NH 12
#define HD 64
#define NEG_MASK (-0x1.FEp+127f)

typedef __attribute__((ext_vector_type(8))) short short8_t;  // 8 bf16
typedef __attribute__((ext_vector_type(4))) float f32x4;     // MFMA C/D + NT stores

static __device__ __forceinline__ unsigned short f2bf(float f) {
  __hip_bfloat16 h = __float2bfloat16(f);
  unsigned short u;
  __builtin_memcpy(&u, &h, 2);
  return u;
}

static __device__ __forceinline__ void st_nt(float* p, f32x4 v) {
  __builtin_nontemporal_store(v, (f32x4*)p);
}
static __device__ __forceinline__ f32x4 ld_lds4(const float* p) {
  return *(const f32x4*)p;
}

// ---------------- LayerNorm -> bf16 ----------------
__global__ __launch_bounds__(256) void ln_kernel(const float* __restrict__ x,
    const float* __restrict__ gamma, const float* __restrict__ beta,
    unsigned short* __restrict__ xnb) {
  int row = blockIdx.x;
  const float* xr = x + (size_t)row * DIM;
  int t = threadIdx.x;
  float v0 = xr[t], v1 = xr[t + 256], v2 = xr[t + 512];
  float s = v0 + v1 + v2;
  float s2 = v0 * v0 + v1 * v1 + v2 * v2;
  for (int off = 32; off > 0; off >>= 1) {
    s += __shfl_down(s, off, 64);
    s2 += __shfl_down(s2, off, 64);
  }
  __shared__ float red[2][4];
  int wid = t >> 6;
  if ((t & 63) == 0) { red[0][wid] = s; red[1][wid] = s2; }
  __syncthreads();
  s = red[0][0] + red[0][1] + red[0][2] + red[0][3];
  s2 = red[1][0] + red[1][1] + red[1][2] + red[1][3];
  float mu = s * (1.0f / DIM);
  float var = s2 * (1.0f / DIM) - mu * mu;
  float rstd = rsqrtf(var + 1e-5f);
  unsigned short* xo = xnb + (size_t)row * DIM;
  xo[t]       = f2bf((v0 - mu) * rstd * gamma[t]       + beta[t]);
  xo[t + 256] = f2bf((v1 - mu) * rstd * gamma[t + 256] + beta[t + 256]);
  xo[t + 512] = f2bf((v2 - mu) * rstd * gamma[t + 512] + beta[t + 512]);
}

// ---------------- weight f32 -> bf16 convert (4 matrices) ----------------
__global__ __launch_bounds__(256) void wcvt_kernel(const float* __restrict__ w0,
    const float* __restrict__ w1, const float* __restrict__ w2, const float* __restrict__ w3,
    unsigned short* __restrict__ o0, unsigned short* __restrict__ o1,
    unsigned short* __restrict__ o2, unsigned short* __restrict__ o3) {
  const float* src; unsigned short* dst;
  switch (blockIdx.y) {
    case 0: src = w0; dst = o0; break;
    case 1: src = w1; dst = o1; break;
    case 2: src = w2; dst = o2; break;
    default: src = w3; dst = o3; break;
  }
  size_t base = ((size_t)blockIdx.x * 256 + threadIdx.x) * 8;
  float4 a = *(const float4*)(src + base);
  float4 b = *(const float4*)(src + base + 4);
  ushort4 ua, ub;
  ua.x = f2bf(a.x); ua.y = f2bf(a.y); ua.z = f2bf(a.z); ua.w = f2bf(a.w);
  ub.x = f2bf(b.x); ub.y = f2bf(b.y); ub.z = f2bf(b.z); ub.w = f2bf(b.w);
  *(ushort4*)(dst + base) = ua;
  *(ushort4*)(dst + base + 4) = ub;
}

// ------- QKV MFMA GEMM + fused RoPE -> bf16 q,k and transposed bf16 v -------
__global__ __launch_bounds__(256) void qkv_kernel(const unsigned short* __restrict__ xnb,
    const unsigned short* __restrict__ wqb, const unsigned short* __restrict__ wkb,
    const unsigned short* __restrict__ wvb, const float* __restrict__ ropes,
    unsigned short* __restrict__ qb, unsigned short* __restrict__ kb,
    unsigned short* __restrict__ vbT) {
  int z = blockIdx.z;
  const unsigned short* W = (z == 0) ? wqb : (z == 1) ? wkb : wvb;
  int h = blockIdx.y;
  int n0 = h * 64;
  int tid = threadIdx.x;
  int w = tid >> 6, l = tid & 63;
  int col_l = l & 15, rowg = l >> 4, kgrp = rowg * 8;
  int mbase = blockIdx.x * 64 + w * 16;

  f32x4 acc[4];
  #pragma unroll
  for (int g = 0; g < 4; g++) acc[g] = (f32x4){0.f, 0.f, 0.f, 0.f};

  for (int k0 = 0; k0 < DIM; k0 += 32) {
    short8_t a = *(const short8_t*)(xnb + (size_t)(mbase + col_l) * DIM + k0 + kgrp);
    #pragma unroll
    for (int g = 0; g < 4; g++) {
      short8_t bw = *(const short8_t*)(W + (size_t)(n0 + g * 16 + col_l) * DIM + k0 + kgrp);
      acc[g] = __builtin_amdgcn_mfma_f32_16x16x32_bf16(a, bw, acc[g], 0, 0, 0);
    }
  }

  // RoPE: d = g*16+col_l, partner d^32 -> acc[g^2], same lane
  float res[4][4];
  #pragma unroll
  for (int g = 0; g < 4; g++) {
    int d = g * 16 + col_l;
    #pragma unroll
    for (int r = 0; r < 4; r++) {
      int m = mbase + rowg * 4 + r;
      float f = ropes[(size_t)m * HD + d];
      float val = acc[g][r];
      float oth = acc[g ^ 2][r];
      float rot = (g < 2) ? -oth : oth;
      res[g][r] = val * cosf(f) + rot * sinf(f);
    }
  }

  if (z < 2) {
    unsigned short* dst = (z == 0) ? qb : kb;
    #pragma unroll
    for (int g = 0; g < 4; g++) {
      int d = g * 16 + col_l;
      #pragma unroll
      for (int r = 0; r < 4; r++)
        dst[((size_t)h * SEQ + mbase + rowg * 4 + r) * HD + d] = f2bf(res[g][r]);
    }
  } else {
    #pragma unroll
    for (int g = 0; g < 4; g++) {
      int d = g * 16 + col_l;
      ushort4 u;
      u.x = f2bf(res[g][0]); u.y = f2bf(res[g][1]);
      u.z = f2bf(res[g][2]); u.w = f2bf(res[g][3]);
      *(ushort4*)(vbT + ((size_t)h * HD + d) * SEQ + mbase + rowg * 4) = u;
    }
  }
}

// ------- fused attention: flat grid + XCD-clustered (h, band) mapping -------
// No-max softmax (logits bounded; masked s=NEG_MASK -> exp==0); NT f32x4 stores.
__global__ __launch_bounds__(256, 4) void attn_fused(
    const unsigned short* __restrict__ qb, const unsigned short* __restrict__ kb,
    const unsigned short* __restrict__ vbT,
    float* __restrict__ dots, float* __restrict__ attnp, unsigned short* __restrict__ ob) {
  int bid = blockIdx.x;                 // 0..3071
  int g_ = (bid & 7) * 384 + (bid >> 3);
  int h = g_ >> 8;                      // 0..11
  int band = 255 - (g_ & 255);          // compute-heavy bands first within chunk
  int i0 = band * 16;
  int jd = i0 >> 6;                    // diagonal 64-tile index
  int tid = threadIdx.x;
  int w = tid >> 6, l = tid & 63;
  int col_l = l & 15, rg = l >> 4, kgrp = rg * 8;
  int c4 = col_l * 4;

  const unsigned short* qh = qb + (size_t)h * SEQ * HD;
  const unsigned short* kh = kb + (size_t)h * SEQ * HD;
  const unsigned short* vh = vbT + (size_t)h * HD * SEQ;
  size_t obase = (size_t)h * SEQ * SEQ;

  __shared__ float pt[4][16][68];
  __shared__ float stats[4][16];       // per-wave row sums

  const unsigned short* qrow = qh + (size_t)(i0 + col_l) * HD + kgrp;
  short8_t aq0 = *(const short8_t*)(qrow);
  short8_t aq1 = *(const short8_t*)(qrow + 32);

  float lsum[4];
  #pragma unroll
  for (int r = 0; r < 4; r++) lsum[r] = 0.f;

  // ---- pass 1: dots + per-lane plain exp-sums ----
  for (int jt = w; jt <= jd; jt += 4) {
    int j0 = jt * 64;
    f32x4 acc[4];
    #pragma unroll
    for (int b = 0; b < 4; b++) {
      const unsigned short* kr = kh + (size_t)(j0 + b * 16 + col_l) * HD + kgrp;
      short8_t bk0 = *(const short8_t*)(kr);
      short8_t bk1 = *(const short8_t*)(kr + 32);
      f32x4 z = {0.f, 0.f, 0.f, 0.f};
      acc[b] = __builtin_amdgcn_mfma_f32_16x16x32_bf16(aq0, bk0, z, 0, 0, 0);
      acc[b] = __builtin_amdgcn_mfma_f32_16x16x32_bf16(aq1, bk1, acc[b], 0, 0, 0);
    }
    bool diag = (jt == jd);
    #pragma unroll
    for (int b = 0; b < 4; b++) {
      int j = j0 + b * 16 + col_l;
      #pragma unroll
      for (int r = 0; r < 4; r++) {
        float s = acc[b][r] * 0.125f;
        acc[b][r] = (diag && j > i0 + rg * 4 + r) ? NEG_MASK : s;
      }
    }
    #pragma unroll
    for (int r = 0; r < 4; r++) {
      lsum[r] += __expf(acc[0][r]) + __expf(acc[1][r]) +
                 __expf(acc[2][r]) + __expf(acc[3][r]);
    }
    // stage + contiguous f32x4 non-temporal dots write
    #pragma unroll
    for (int b = 0; b < 4; b++)
      #pragma unroll
      for (int r = 0; r < 4; r++)
        pt[w][rg * 4 + r][b * 16 + col_l] = acc[b][r];
    #pragma unroll
    for (int e = 0; e < 4; e++) {
      f32x4 v = ld_lds4(&pt[w][e * 4 + rg][c4]);
      st_nt(dots + obase + (size_t)(i0 + e * 4 + rg) * SEQ + j0 + c4, v);
    }
  }

  // ---- reduction: 16-lane sum + 4-wave sum via LDS ----
  #pragma unroll
  for (int r = 0; r < 4; r++) {
    #pragma unroll
    for (int off = 1; off < 16; off <<= 1)
      lsum[r] += __shfl_xor(lsum[r], off, 16);
  }
  if (col_l == 0) {
    #pragma unroll
    for (int r = 0; r < 4; r++)
      stats[w][rg * 4 + r] = lsum[r];
  }
  __syncthreads();
  float rl_[4];
  #pragma unroll
  for (int r = 0; r < 4; r++) {
    int row = rg * 4 + r;
    rl_[r] = 1.0f / (stats[0][row] + stats[1][row] + stats[2][row] + stats[3][row]);
  }

  // ---- pass 2: attn + partial PV ----
  f32x4 o[4];
  #pragma unroll
  for (int dg = 0; dg < 4; dg++) o[dg] = (f32x4){0.f, 0.f, 0.f, 0.f};

  for (int jt = w; jt <= jd; jt += 4) {
    int j0 = jt * 64;
    f32x4 acc[4];
    #pragma unroll
    for (int b = 0; b < 4; b++) {
      const unsigned short* kr = kh + (size_t)(j0 + b * 16 + col_l) * HD + kgrp;
      short8_t bk0 = *(const short8_t*)(kr);
      short8_t bk1 = *(const short8_t*)(kr + 32);
      f32x4 z = {0.f, 0.f, 0.f, 0.f};
      acc[b] = __builtin_amdgcn_mfma_f32_16x16x32_bf16(aq0, bk0, z, 0, 0, 0);
      acc[b] = __builtin_amdgcn_mfma_f32_16x16x32_bf16(aq1, bk1, acc[b], 0, 0, 0);
    }
    bool diag = (jt == jd);
    #pragma unroll
    for (int b = 0; b < 4; b++) {
      int j = j0 + b * 16 + col_l;
      #pragma unroll
      for (int r = 0; r < 4; r++) {
        float s = acc[b][r] * 0.125f;
        s = (diag && j > i0 + rg * 4 + r) ? NEG_MASK : s;
        float p = __expf(s) * rl_[r];
        pt[w][rg * 4 + r][b * 16 + col_l] = p;
      }
    }
    // contiguous f32x4 non-temporal attn write
    #pragma unroll
    for (int e = 0; e < 4; e++) {
      f32x4 v = ld_lds4(&pt[w][e * 4 + rg][c4]);
      st_nt(attnp + obase + (size_t)(i0 + e * 4 + rg) * SEQ + j0 + c4, v);
    }
    // wave-local transpose -> PV
    short8_t pa[2];
    #pragma unroll
    for (int ks = 0; ks < 2; ks++) {
      const float* src = &pt[w][col_l][ks * 32 + kgrp];
      f32x4 x0 = ld_lds4(src);
      f32x4 x1 = ld_lds4(src + 4);
      short8_t t;
      t[0] = (short)f2bf(x0.x); t[1] = (short)f2bf(x0.y);
      t[2] = (short)f2bf(x0.z); t[3] = (short)f2bf(x0.w);
      t[4] = (short)f2bf(x1.x); t[5] = (short)f2bf(x1.y);
      t[6] = (short)f2bf(x1.z); t[7] = (short)f2bf(x1.w);
      pa[ks] = t;
    }
    #pragma unroll
    for (int dg = 0; dg < 4; dg++) {
      const unsigned short* vr = vh + (size_t)(dg * 16 + col_l) * SEQ + j0 + kgrp;
      short8_t bv0 = *(const short8_t*)(vr);
      short8_t bv1 = *(const short8_t*)(vr + 32);
      o[dg] = __builtin_amdgcn_mfma_f32_16x16x32_bf16(pa[0], bv0, o[dg], 0, 0, 0);
      o[dg] = __builtin_amdgcn_mfma_f32_16x16x32_bf16(pa[1], bv1, o[dg], 0, 0, 0);
    }
  }

  // ---- masked-region fill: cols >= (jd+1)*64, rows i0..i0+15 (non-temporal) ----
  {
    int c0 = (jd + 1) * 64;
    int nf4 = (SEQ - c0) >> 2;
    if (nf4 > 0) {
      f32x4 dm = (f32x4){NEG_MASK, NEG_MASK, NEG_MASK, NEG_MASK};
      f32x4 zz = (f32x4){0.f, 0.f, 0.f, 0.f};
      for (int r16 = 0; r16 < 16; r16++) {
        float* dr = dots  + obase + (size_t)(i0 + r16) * SEQ + c0;
        float* ar = attnp + obase + (size_t)(i0 + r16) * SEQ + c0;
        for (int c = tid; c < nf4; c += 256) {
          st_nt(dr + c * 4, dm);
          st_nt(ar + c * 4, zz);
        }
      }
    }
  }

  // ---- cross-wave O reduce -> bf16 ob ----
  __syncthreads();   // all waves done with pt (pass 2)
  #pragma unroll
  for (int dg = 0; dg < 4; dg++)
    #pragma unroll
    for (int r = 0; r < 4; r++)
      pt[w][rg * 4 + r][dg * 16 + col_l] = o[dg][r];
  __syncthreads();
  {
    int idx = tid * 4;                // 0..1020
    int row = idx >> 6, col = idx & 63;
    f32x4 s = ld_lds4(&pt[0][row][col]);
    #pragma unroll
    for (int w2 = 1; w2 < 4; w2++) {
      f32x4 t = ld_lds4(&pt[w2][row][col]);
      s.x += t.x; s.y += t.y; s.z += t.z; s.w += t.w;
    }
    ushort4 u;
    u.x = f2bf(s.x); u.y = f2bf(s.y); u.z = f2bf(s.z); u.w = f2bf(s.w);
    *(ushort4*)(ob + (size_t)(i0 + row) * DIM + h * HD + col) = u;
  }
}

// ---------------- out = o @ Wo^T + bo + residual (MFMA) ----------------
__global__ __launch_bounds__(256) void out_kernel(const unsigned short* __restrict__ ob,
    const unsigned short* __restrict__ wob, const float* __restrict__ bias,
    const float* __restrict__ resid, float* __restrict__ out) {
  int n0 = blockIdx.y * 64;
  int tid = threadIdx.x;
  int w = tid >> 6, l = tid & 63;
  int col_l = l & 15, rowg = l >> 4, kgrp = rowg * 8;
  int mbase = blockIdx.x * 64 + w * 16;

  f32x4 acc[4];
  #pragma unroll
  for (int g = 0; g < 4; g++) acc[g] = (f32x4){0.f, 0.f, 0.f, 0.f};

  for (int k0 = 0; k0 < DIM; k0 += 32) {
    short8_t a = *(const short8_t*)(ob + (size_t)(mbase + col_l) * DIM + k0 + kgrp);
    #pragma unroll
    for (int g = 0; g < 4; g++) {
      short8_t bw = *(const short8_t*)(wob + (size_t)(n0 + g * 16 + col_l) * DIM + k0 + kgrp);
      acc[g] = __builtin_amdgcn_mfma_f32_16x16x32_bf16(a, bw, acc[g], 0, 0, 0);
    }
  }
  #pragma unroll
  for (int g = 0; g < 4; g++) {
    int n = n0 + g * 16 + col_l;
    float bn = bias[n];
    #pragma unroll
    for (int r = 0; r < 4; r++) {
      int m = mbase + rowg * 4 + r;
      out[(size_t)m * DIM + n] = acc[g][r] + bn + resid[(size_t)m * DIM + n];
    }
  }
}

extern "C" void kernel_launch(void* const* d_in, const int* in_sizes, int n_in,
                              void* d_out, int out_size, void* d_ws, size_t ws_size,
                              hipStream_t stream) {
  const float* x     = (const float*)d_in[0];
  const float* Wq    = (const float*)d_in[1];
  const float* Wk    = (const float*)d_in[2];
  const float* Wv    = (const float*)d_in[3];
  const float* Wo    = (const float*)d_in[4];
  const float* bo    = (const float*)d_in[5];
  const float* gamma = (const float*)d_in[6];
  const float* beta  = (const float*)d_in[7];
  const float* rope  = (const float*)d_in[8];

  float* out  = (float*)d_out;                       // [1,4096,768]
  float* attn = out + (size_t)SEQ * DIM;             // [1,12,4096,4096]
  float* dots = attn + (size_t)NH * SEQ * SEQ;       // [1,12,4096,4096]

  char* ws = (char*)d_ws;
  unsigned short* xnb = (unsigned short*)(ws);                    // 6291456 B
  unsigned short* qb  = (unsigned short*)(ws + 6291456);          // 6291456
  unsigned short* kb  = (unsigned short*)(ws + 12582912);         // 6291456
  unsigned short* vbT = (unsigned short*)(ws + 18874368);         // 6291456
  unsigned short* ob  = (unsigned short*)(ws + 25165824);         // 6291456
  unsigned short* wqb = (unsigned short*)(ws + 31457280);         // 1179648
  unsigned short* wkb = (unsigned short*)(ws + 32636928);         // 1179648
  unsigned short* wvb = (unsigned short*)(ws + 33816576);         // 1179648
  unsigned short* wob = (unsigned short*)(ws + 34996224);         // 1179648

  ln_kernel<<<SEQ, 256, 0, stream>>>(x, gamma, beta, xnb);
  wcvt_kernel<<<dim3(288, 4), 256, 0, stream>>>(Wq, Wk, Wv, Wo, wqb, wkb, wvb, wob);
  qkv_kernel<<<dim3(SEQ / 64, NH, 3), 256, 0, stream>>>(xnb, wqb, wkb, wvb, rope, qb, kb, vbT);
  attn_fused<<<3072, 256, 0, stream>>>(qb, kb, vbT, dots, attn, ob);
  out_kernel<<<dim3(SEQ / 64, DIM / 64), 256, 0, stream>>>(ob, wob, bo, x, out);
}